// Round 1
// 1000.843 us; speedup vs baseline: 1.0063x; 1.0063x over previous
//
#include <hip/hip_runtime.h>
#include <math.h>

// TrittentionCube: B=16, S=512, HID=2048, H=4, D=512 (S==D)
// Round 6: proj staging switched from reg round-trip to async
// global_load_lds (width=16, m97 structure). LDS layout is unchanged
// (fragment-order slots are linear in thread order = wave base + lane*16),
// only the transport changed: per-lane global addr -> wave-uniform LDS base.
// Chain kernel unchanged.

typedef _Float16 f16;
typedef f16 f16x8 __attribute__((ext_vector_type(8)));
typedef float f32x4 __attribute__((ext_vector_type(4)));
typedef float f32x16 __attribute__((ext_vector_type(16)));

#define SB_STRIDE 520            // S-buffer row stride (halfs): 2-way bank alias = free
#define BP_HALF   16384          // 32 KB panel buffer (halfs)
#define CHAIN_LDS ((64 * SB_STRIDE + 2 * BP_HALF) * 2)   // 132,096 B

static constexpr float SCALE = 0.04419417382415922f;  // 1/sqrt(512)

// async global->LDS, 16B per lane; LDS dest = wave-uniform base + lane*16
__device__ __forceinline__ void gl_lds16(const f16* g, f16* l)
{
    __builtin_amdgcn_global_load_lds(
        (const __attribute__((address_space(1))) void*)g,
        (__attribute__((address_space(3))) void*)l, 16, 0, 0);
}

// ---------------------------------------------------------------- convert
__global__ __launch_bounds__(256) void conv_f32_f16(const float* __restrict__ src,
                                                    f16* __restrict__ dst, int n)
{
    int i = (blockIdx.x * 256 + threadIdx.x) * 8;
    if (i + 8 <= n) {
        float4 a = *(const float4*)(src + i);
        float4 b = *(const float4*)(src + i + 4);
        f16 o[8] = {(f16)a.x, (f16)a.y, (f16)a.z, (f16)a.w,
                    (f16)b.x, (f16)b.y, (f16)b.z, (f16)b.w};
        *(int4*)(dst + i) = *(int4*)o;
    }
}

// ---------------------------------------------------------------- projections
struct ProjPtrs {
    const f16* W[5];
    const float* bias[5];
    f16* dst[5];
};

// C[m,n] = sum_k A[m,k] * W[n,k] + bias[n]. Block 128x128, BK=32, 4 waves
// (2x2 of 64x64), 16x16x32_f16. LDS fragment-order: slot s (512 slots of 16B)
// = [mblk=s>>6][kgrp=(s>>4)&3][row=s&15][8 halfs]. Slot s is staged by
// global_load_lds: wave w's 4 issues cover slots {w*64..w*64+63} (+256 for
// the second m/n half) -- LDS dest wave-uniform, global addr per-lane.
// Frag reads are 1024B-contiguous per wave (2-way bank alias = free).
// z==2 (v) and z==4 (cv) are stored transposed [bh][d][s] for the chain.
__global__ __launch_bounds__(256) void proj_f16(const f16* __restrict__ A, ProjPtrs P)
{
    __shared__ f16 AsF[4096];   // 8 KB
    __shared__ f16 BsF[4096];
    const int z = blockIdx.z;
    const f16* __restrict__ W = P.W[z];
    const float* __restrict__ bias = P.bias[z];
    f16* __restrict__ dst = P.dst[z];
    const bool tr = (z == 2) || (z == 4);

    const int t    = threadIdx.x;
    const int lane = t & 63;
    const int wave = t >> 6;
    const int bm = blockIdx.y * 128, bn = blockIdx.x * 128;

    // per-lane global source for slots t (mblk 0..3) and t+256 (mblk 4..7)
    const int srow = (t >> 6) * 16 + (t & 15);   // row within 128-tile
    const int skc  = ((t >> 4) & 3) * 8;         // k offset (halfs)
    const f16* aP0 = A + (size_t)(bm + srow) * 2048 + skc;
    const f16* aP1 = aP0 + (size_t)64 * 2048;    // mblk + 4
    const f16* bP0 = W + (size_t)(bn + srow) * 2048 + skc;
    const f16* bP1 = bP0 + (size_t)64 * 2048;

    // wave-uniform LDS destinations (HW adds lane*16B)
    f16* ldsA0 = AsF + wave * 512;
    f16* ldsA1 = AsF + 2048 + wave * 512;
    f16* ldsB0 = BsF + wave * 512;
    f16* ldsB1 = BsF + 2048 + wave * 512;

    const int wmB = (wave >> 1) * 4;    // wave's first m-block
    const int wnB = (wave & 1) * 4;     // wave's first n-block

    f32x4 acc[4][4];
#pragma unroll
    for (int i = 0; i < 4; ++i)
#pragma unroll
        for (int j = 0; j < 4; ++j)
#pragma unroll
            for (int r = 0; r < 4; ++r) acc[i][j][r] = 0.f;

    for (int k0 = 0; k0 < 2048; k0 += 32) {
        __syncthreads();                 // all frag reads of prev tile done
        gl_lds16(aP0 + k0, ldsA0);
        gl_lds16(aP1 + k0, ldsA1);
        gl_lds16(bP0 + k0, ldsB0);
        gl_lds16(bP1 + k0, ldsB1);
        __syncthreads();                 // vmcnt drain + barrier: tile visible

        f16x8 af[4], bf[4];
#pragma unroll
        for (int mt = 0; mt < 4; ++mt)
            af[mt] = *(const f16x8*)(AsF + (wmB + mt) * 512 + lane * 8);
#pragma unroll
        for (int nt = 0; nt < 4; ++nt)
            bf[nt] = *(const f16x8*)(BsF + (wnB + nt) * 512 + lane * 8);
#pragma unroll
        for (int mt = 0; mt < 4; ++mt)
#pragma unroll
            for (int nt = 0; nt < 4; ++nt)
                acc[mt][nt] = __builtin_amdgcn_mfma_f32_16x16x32_f16(af[mt], bf[nt], acc[mt][nt], 0, 0, 0);
    }

    // epilogue: C/D mapping col(n)=lane&15, row(m)=(lane>>4)*4+reg
    const int wm = (wave >> 1) * 64, wn = (wave & 1) * 64;
#pragma unroll
    for (int nt = 0; nt < 4; ++nt) {
        int n = bn + wn + nt * 16 + (lane & 15);
        float bb = bias[n];
        int h = n >> 9, d = n & 511;
#pragma unroll
        for (int mt = 0; mt < 4; ++mt) {
            int mbase = bm + wm + mt * 16 + (lane >> 4) * 4;
            int b = mbase >> 9, s0 = mbase & 511;
            if (!tr) {
#pragma unroll
                for (int r = 0; r < 4; ++r)
                    dst[(((size_t)(b * 4 + h)) * 512 + s0 + r) * 512 + d] =
                        (f16)(acc[mt][nt][r] + bb);
            } else {
                f16 pk[4];
#pragma unroll
                for (int r = 0; r < 4; ++r) pk[r] = (f16)(acc[mt][nt][r] + bb);
                *(float2*)(dst + (((size_t)(b * 4 + h)) * 512 + d) * 512 + s0) =
                    *(float2*)pk;
            }
        }
    }
}

// ---------------------------------------------------------------- fused chain
// 512 threads, 8 waves; wave w owns 64-col n-strip, acc[2][2] (64x512 tile).
// acc = Sb(64xK=512) @ Bsrc^T, Bsrc row-major [n][k] (ld=512).
// B-panel (k=32) layout: [nb 16][ks 2][n 32][8 halfs], double-buffered,
// staged with global_load_lds; panel p+1 in flight during panel p compute.
__device__ __forceinline__ void stage_nt(
    const f16* __restrict__ Bsrc,
    f16* __restrict__ Sb, f16* __restrict__ Bp, int t, f32x16 acc[2][2])
{
    const int lane = t & 63;
    const int wave = t >> 6;
    const int l31  = lane & 31;
    const int l5   = (lane >> 5) * 8;

#pragma unroll
    for (int mt = 0; mt < 2; ++mt)
#pragma unroll
        for (int nt = 0; nt < 2; ++nt)
#pragma unroll
            for (int r = 0; r < 16; ++r) acc[mt][nt][r] = 0.f;

    // issue panel 0 -> buf0 (safe: prior reads of buf0 ended before caller's sync)
#pragma unroll
    for (int it = 0; it < 4; ++it) {
        int nb = wave * 2 + (it & 1), ks = it >> 1;
        gl_lds16(Bsrc + (size_t)(nb * 32 + l31) * 512 + ks * 16 + l5,
                 Bp + nb * 1024 + ks * 512);
    }

    for (int p = 0; p < 16; ++p) {
        const int k0 = p * 32;
        __syncthreads();   // panel p landed (vmcnt drain); buf[(p+1)&1] free
        if (p < 15) {
            f16* nbuf = Bp + ((p + 1) & 1) * BP_HALF;
#pragma unroll
            for (int it = 0; it < 4; ++it) {
                int nb = wave * 2 + (it & 1), ks = it >> 1;
                gl_lds16(Bsrc + (size_t)(nb * 32 + l31) * 512 + k0 + 32 + ks * 16 + l5,
                         nbuf + nb * 1024 + ks * 512);
            }
        }
        const f16* cbuf = Bp + (p & 1) * BP_HALF;
#pragma unroll
        for (int dk = 0; dk < 32; dk += 16) {
            f16x8 af[2], bf[2];
#pragma unroll
            for (int mt = 0; mt < 2; ++mt)
                af[mt] = *(const f16x8*)(Sb + (size_t)(mt * 32 + l31) * SB_STRIDE + k0 + dk + l5);
#pragma unroll
            for (int nt = 0; nt < 2; ++nt)
                bf[nt] = *(const f16x8*)(cbuf + (wave * 2 + nt) * 1024 + (dk >> 4) * 512 + lane * 8);
#pragma unroll
            for (int mt = 0; mt < 2; ++mt)
#pragma unroll
                for (int nt = 0; nt < 2; ++nt)
                    acc[mt][nt] = __builtin_amdgcn_mfma_f32_32x32x16_f16(af[mt], bf[nt], acc[mt][nt], 0, 0, 0);
        }
    }
    __syncthreads();  // all waves done reading Sb/Bp -> caller may overwrite Sb
}

// C/D mapping 32x32: col=lane&31, row=(reg&3)+8*(reg>>2)+4*(lane>>5)
__device__ __forceinline__ void emit_to_S(f16* __restrict__ Sb, const f32x16 acc[2][2],
                                          int t, float scale)
{
    const int lane = t & 63;
    const int wn = (t >> 6) * 64;
#pragma unroll
    for (int mt = 0; mt < 2; ++mt)
#pragma unroll
        for (int nt = 0; nt < 2; ++nt) {
            int col = wn + nt * 32 + (lane & 31);
#pragma unroll
            for (int r = 0; r < 16; ++r) {
                int row = mt * 32 + (r & 3) + 8 * (r >> 2) + 4 * (lane >> 5);
                Sb[(size_t)row * SB_STRIDE + col] = (f16)(acc[mt][nt][r] * scale);
            }
        }
}

__global__ __launch_bounds__(512) void chain_f16(
    const f16* __restrict__ q16, const f16* __restrict__ k16,
    const f16* __restrict__ ck16, const f16* __restrict__ vt16,
    const f16* __restrict__ cvt16, float* __restrict__ out)
{
    extern __shared__ f16 smem[];
    f16* Sb = smem;                       // [64][SB_STRIDE]
    f16* Bp = smem + 64 * SB_STRIDE;      // 2 x BP_HALF
    const int t = threadIdx.x;
    const int bh = blockIdx.x >> 3;
    const int q0 = (blockIdx.x & 7) * 64;
    const size_t SB = 512 * 512;

    // stage Q[q0..q0+64) into Sbuf
    const f16* Q = q16 + bh * SB;
    for (int i = t; i < 4096; i += 512) {
        int row = i >> 6, c = (i & 63) * 8;
        *(int4*)(Sb + (size_t)row * SB_STRIDE + c) =
            *(const int4*)(Q + (size_t)(q0 + row) * 512 + c);
    }
    // stage_nt's loop-top sync covers Q-write -> Sb-read

    f32x16 acc[2][2];

    // S1 = Q @ K^T
    stage_nt(k16 + bh * SB, Sb, Bp, t, acc);
    emit_to_S(Sb, acc, t, 1.0f);

    // S2 = S1 @ CK^T * SCALE
    stage_nt(ck16 + bh * SB, Sb, Bp, t, acc);
    emit_to_S(Sb, acc, t, SCALE);
    __syncthreads();

    // softmax rows (wave w -> rows 8w..8w+8)
    {
        const int lane = t & 63;
        const int wave = t >> 6;
        for (int rr = 0; rr < 8; ++rr) {
            int r = wave * 8 + rr;
            f16x8 xv = *(const f16x8*)(Sb + (size_t)r * SB_STRIDE + lane * 8);
            float x[8];
            float mx = -1e30f;
#pragma unroll
            for (int j = 0; j < 8; ++j) { x[j] = (float)xv[j]; mx = fmaxf(mx, x[j]); }
#pragma unroll
            for (int o = 32; o > 0; o >>= 1) mx = fmaxf(mx, __shfl_xor(mx, o));
            float s = 0.f;
#pragma unroll
            for (int j = 0; j < 8; ++j) { x[j] = __expf(x[j] - mx); s += x[j]; }
#pragma unroll
            for (int o = 32; o > 0; o >>= 1) s += __shfl_xor(s, o);
            float inv = 1.0f / s;
            f16x8 ov;
#pragma unroll
            for (int j = 0; j < 8; ++j) ov[j] = (f16)(x[j] * inv);
            *(f16x8*)(Sb + (size_t)r * SB_STRIDE + lane * 8) = ov;
        }
    }
    // stage_nt's loop-top sync covers softmax-write -> Sb-read

    // C1 = P @ V   (Vt is [bh][d][s]: NT-ready)
    stage_nt(vt16 + bh * SB, Sb, Bp, t, acc);
    emit_to_S(Sb, acc, t, 1.0f);

    // OUT = C1 @ CV (CVt NT-ready), merge-heads store f32
    stage_nt(cvt16 + bh * SB, Sb, Bp, t, acc);
    {
        const int lane = t & 63;
        const int wn = (t >> 6) * 64;
        int b = bh >> 2, h = bh & 3;
#pragma unroll
        for (int mt = 0; mt < 2; ++mt)
#pragma unroll
            for (int nt = 0; nt < 2; ++nt) {
                int col = h * 512 + wn + nt * 32 + (lane & 31);
#pragma unroll
                for (int r = 0; r < 16; ++r) {
                    int row = q0 + mt * 32 + (r & 3) + 8 * (r >> 2) + 4 * (lane >> 5);
                    out[((size_t)b * 512 + row) * 2048 + col] = acc[mt][nt][r];
                }
            }
    }
}

// ---------------------------------------------------------------- host
extern "C" void kernel_launch(void* const* d_in, const int* in_sizes, int n_in,
                              void* d_out, int out_size, void* d_ws, size_t ws_size,
                              hipStream_t stream)
{
    const float* hs = (const float*)d_in[0];
    const float* Wf[5] = {(const float*)d_in[1], (const float*)d_in[3],
                          (const float*)d_in[5], (const float*)d_in[7],
                          (const float*)d_in[9]};
    const float* bf[5] = {(const float*)d_in[2], (const float*)d_in[4],
                          (const float*)d_in[6], (const float*)d_in[8],
                          (const float*)d_in[10]};
    float* out = (float*)d_out;

    hipFuncSetAttribute((const void*)chain_f16,
                        hipFuncAttributeMaxDynamicSharedMemorySize, CHAIN_LDS);

    f16* ws = (f16*)d_ws;
    const size_t WELEM = 2048ULL * 2048;      // 4,194,304
    const size_t FULLACT = 64ULL * 512 * 512; // 16,777,216

    f16* W16[5];
    for (int i = 0; i < 5; ++i) W16[i] = ws + i * WELEM;
    f16* after_w = ws + 5 * WELEM;

    for (int i = 0; i < 5; ++i)
        conv_f32_f16<<<dim3(WELEM / 2048), 256, 0, stream>>>(Wf[i], W16[i], (int)WELEM);

    size_t full_need = (5 * WELEM + FULLACT + 5 * FULLACT) * sizeof(f16);  // 243,269,632
    if (ws_size >= full_need) {
        // ---------------- full path ----------------
        f16* hs16 = after_w;
        f16* act[5];
        for (int i = 0; i < 5; ++i) act[i] = after_w + FULLACT + i * FULLACT;

        conv_f32_f16<<<dim3(FULLACT / 2048), 256, 0, stream>>>(hs, hs16, (int)FULLACT);

        ProjPtrs P;
        for (int i = 0; i < 5; ++i) { P.W[i] = W16[i]; P.bias[i] = bf[i]; P.dst[i] = act[i]; }
        proj_f16<<<dim3(16, 64, 5), 256, 0, stream>>>(hs16, P);

        // act order: q,k,v^T,ck,cv^T -> chain(q,k,ck,vt,cvt)
        chain_f16<<<dim3(512), 512, CHAIN_LDS, stream>>>(
            act[0], act[1], act[3], act[2], act[4], out);
    } else {
        // ---------------- chunked path (54.5 MB ws) ----------------
        const size_t CHROW = 1048576ULL;      // 512*2048 elems per batch
        const size_t CHACT = 4ULL * 512 * 512;
        f16* hs16c = after_w;
        f16* act[5];
        for (int i = 0; i < 5; ++i) act[i] = after_w + CHROW + i * CHACT;

        ProjPtrs P;
        for (int i = 0; i < 5; ++i) { P.W[i] = W16[i]; P.bias[i] = bf[i]; P.dst[i] = act[i]; }

        for (int c = 0; c < 16; ++c) {
            conv_f32_f16<<<dim3(CHROW / 2048), 256, 0, stream>>>(
                hs + c * CHROW, hs16c, (int)CHROW);
            proj_f16<<<dim3(16, 4, 5), 256, 0, stream>>>(hs16c, P);
            chain_f16<<<dim3(32), 512, CHAIN_LDS, stream>>>(
                act[0], act[1], act[3], act[2], act[4], out + c * CHROW);
        }
    }

    (void)in_sizes; (void)n_in; (void)out_size;
}

// Round 2
// 783.151 us; speedup vs baseline: 1.2860x; 1.2780x over previous
//
#include <hip/hip_runtime.h>
#include <math.h>

// TrittentionCube: B=16, S=512, HID=2048, H=4, D=512 (S==D)
// Round 7: proj rewritten as 256x256-tile, BK=32, 4-deep global_load_lds
// pipeline (4 x 32KB LDS buffers), ONE raw s_barrier + counted vmcnt(8)
// per K-tile (T3+T4), setprio around MFMA cluster (T5). Fragment-order LDS
// keeps both staging and b128 frag reads conflict-free with no swizzle.
// Chain kernel unchanged.

typedef _Float16 f16;
typedef f16 f16x8 __attribute__((ext_vector_type(8)));
typedef float f32x4 __attribute__((ext_vector_type(4)));
typedef float f32x16 __attribute__((ext_vector_type(16)));

#define SB_STRIDE 520            // chain S-buffer row stride (halfs)
#define BP_HALF   16384          // chain 32 KB panel buffer (halfs)
#define CHAIN_LDS ((64 * SB_STRIDE + 2 * BP_HALF) * 2)   // 132,096 B
#define PROJ_LDS  131072         // 4 x 32KB K-tile buffers

static constexpr float SCALE = 0.04419417382415922f;  // 1/sqrt(512)

// async global->LDS, 16B per lane; LDS dest = wave-uniform base + lane*16
__device__ __forceinline__ void gl_lds16(const f16* g, f16* l)
{
    __builtin_amdgcn_global_load_lds(
        (const __attribute__((address_space(1))) void*)g,
        (__attribute__((address_space(3))) void*)l, 16, 0, 0);
}

// ---------------------------------------------------------------- convert
__global__ __launch_bounds__(256) void conv_f32_f16(const float* __restrict__ src,
                                                    f16* __restrict__ dst, int n)
{
    int i = (blockIdx.x * 256 + threadIdx.x) * 8;
    if (i + 8 <= n) {
        float4 a = *(const float4*)(src + i);
        float4 b = *(const float4*)(src + i + 4);
        f16 o[8] = {(f16)a.x, (f16)a.y, (f16)a.z, (f16)a.w,
                    (f16)b.x, (f16)b.y, (f16)b.z, (f16)b.w};
        *(int4*)(dst + i) = *(int4*)o;
    }
}

// ---------------------------------------------------------------- projections
struct ProjPtrs {
    const f16* W[5];
    const float* bias[5];
    f16* dst[5];
};

// C[m,n] = sum_k A[m,k] * W[n,k] + bias[n].  Block 256x256, BK=32,
// 512 threads = 8 waves as 2(M) x 4(N); per-wave output 128x64,
// acc[8][4] of 16x16x32_f16 fragments (128 acc VGPRs).
//
// LDS: 4 buffers x 32KB (A-tile 16KB + B-tile 16KB each).  Tile layout is
// fragment-order: [rg = row>>4][kg = k-chunk][row&15][8 halfs] so that
//   - staging is lane-linear: thread t writes byte t*16 of each half
//     (global_load_lds wave-uniform dest + lane*16), and
//   - frag reads af/bf are 1KB-contiguous ds_read_b128 (conflict-free).
//
// Pipeline: prologue stages tiles 0..2; iteration kt waits its own tile with
// counted vmcnt (8 = 2 tiles in flight), one s_barrier, then stages tile
// kt+3 into the buffer freed at kt-1, then computes tile kt.  ~3 K-tiles
// (~1000 cyc) of latency slack; vmcnt never drains to 0 until the tail.
// z==2 (v) and z==4 (cv) are stored transposed [bh][d][s] for the chain.
__global__ __launch_bounds__(512, 2) void proj_f16(const f16* __restrict__ A, ProjPtrs P)
{
    extern __shared__ f16 sm[];          // 4 * 16384 halfs = 128 KB
    const int z = blockIdx.z;
    const f16* __restrict__ W = P.W[z];
    const float* __restrict__ bias = P.bias[z];
    f16* __restrict__ dst = P.dst[z];
    const bool tr = (z == 2) || (z == 4);

    const int t    = threadIdx.x;
    const int lane = t & 63;
    const int wave = t >> 6;
    const int wr   = wave >> 2, wc = wave & 3;
    const int bm = blockIdx.y * 256, bn = blockIdx.x * 256;

    // per-thread global staging bases: row = bm/bn + half*128 + wave*16 + r16,
    // k-offset = kg*8 halfs
    const int r16 = lane & 15;
    const int kg  = (lane >> 4) & 3;
    const f16* aB0 = A + (size_t)(bm + wave * 16 + r16) * 2048 + kg * 8;
    const f16* aB1 = aB0 + (size_t)128 * 2048;
    const f16* bB0 = W + (size_t)(bn + wave * 16 + r16) * 2048 + kg * 8;
    const f16* bB1 = bB0 + (size_t)128 * 2048;

// stage K-tile (A 16KB: halves rg0-7 / rg8-15; B same) into buffer j
#define STAGE(j, k0)                                          \
    {                                                         \
        f16* bp = sm + (j) * 16384 + wave * 512;              \
        gl_lds16(aB0 + (k0), bp);                             \
        gl_lds16(aB1 + (k0), bp + 4096);                      \
        gl_lds16(bB0 + (k0), bp + 8192);                      \
        gl_lds16(bB1 + (k0), bp + 12288);                     \
    }

    f32x4 acc[8][4];
#pragma unroll
    for (int mf = 0; mf < 8; ++mf)
#pragma unroll
        for (int nf = 0; nf < 4; ++nf)
#pragma unroll
            for (int r = 0; r < 4; ++r) acc[mf][nf][r] = 0.f;

    // prologue: 3 tiles in flight (12 vmem instrs/wave)
    STAGE(0, 0);
    STAGE(1, 32);
    STAGE(2, 64);

    const int lkoff = (lane >> 4) * 128 + r16 * 8;   // frag-read offset (halfs)

    for (int kt = 0; kt < 64; ++kt) {
        // wait: tile kt landed (counted -- tiles kt+1..kt+2 stay in flight)
        if (kt < 62)       asm volatile("s_waitcnt vmcnt(8)" ::: "memory");
        else if (kt == 62) asm volatile("s_waitcnt vmcnt(4)" ::: "memory");
        else               asm volatile("s_waitcnt vmcnt(0)" ::: "memory");
        __builtin_amdgcn_s_barrier();    // everyone's tile-kt landed; all
        asm volatile("" ::: "memory");   // reads of tile kt-1 retired

        if (kt + 3 < 64) STAGE((kt + 3) & 3, (kt + 3) * 32);

        const f16* bufA = sm + (kt & 3) * 16384;
        const f16* bufB = bufA + 8192;

        f16x8 af[8], bf[4];
#pragma unroll
        for (int mf = 0; mf < 8; ++mf)
            af[mf] = *(const f16x8*)(bufA + (wr * 8 + mf) * 512 + lkoff);
#pragma unroll
        for (int nf = 0; nf < 4; ++nf)
            bf[nf] = *(const f16x8*)(bufB + (wc * 4 + nf) * 512 + lkoff);

        __builtin_amdgcn_s_setprio(1);
#pragma unroll
        for (int mf = 0; mf < 8; ++mf)
#pragma unroll
            for (int nf = 0; nf < 4; ++nf)
                acc[mf][nf] = __builtin_amdgcn_mfma_f32_16x16x32_f16(
                    af[mf], bf[nf], acc[mf][nf], 0, 0, 0);
        __builtin_amdgcn_s_setprio(0);
    }
#undef STAGE

    // epilogue: C/D mapping col(n)=lane&15, row(m)=(lane>>4)*4+reg
    const int wm = wr * 128, wn = wc * 64;
#pragma unroll
    for (int nf = 0; nf < 4; ++nf) {
        int n = bn + wn + nf * 16 + r16;
        float bb = bias[n];
        int h = n >> 9, d = n & 511;
#pragma unroll
        for (int mf = 0; mf < 8; ++mf) {
            int mbase = bm + wm + mf * 16 + (lane >> 4) * 4;
            int b = mbase >> 9, s0 = mbase & 511;
            if (!tr) {
#pragma unroll
                for (int r = 0; r < 4; ++r)
                    dst[(((size_t)(b * 4 + h)) * 512 + s0 + r) * 512 + d] =
                        (f16)(acc[mf][nf][r] + bb);
            } else {
                f16 pk[4];
#pragma unroll
                for (int r = 0; r < 4; ++r) pk[r] = (f16)(acc[mf][nf][r] + bb);
                *(float2*)(dst + (((size_t)(b * 4 + h)) * 512 + d) * 512 + s0) =
                    *(float2*)pk;
            }
        }
    }
}

// ---------------------------------------------------------------- fused chain
// 512 threads, 8 waves; wave w owns 64-col n-strip, acc[2][2] (64x512 tile).
// acc = Sb(64xK=512) @ Bsrc^T, Bsrc row-major [n][k] (ld=512).
// B-panel (k=32) layout: [nb 16][ks 2][n 32][8 halfs], double-buffered,
// staged with global_load_lds; panel p+1 in flight during panel p compute.
__device__ __forceinline__ void stage_nt(
    const f16* __restrict__ Bsrc,
    f16* __restrict__ Sb, f16* __restrict__ Bp, int t, f32x16 acc[2][2])
{
    const int lane = t & 63;
    const int wave = t >> 6;
    const int l31  = lane & 31;
    const int l5   = (lane >> 5) * 8;

#pragma unroll
    for (int mt = 0; mt < 2; ++mt)
#pragma unroll
        for (int nt = 0; nt < 2; ++nt)
#pragma unroll
            for (int r = 0; r < 16; ++r) acc[mt][nt][r] = 0.f;

    // issue panel 0 -> buf0 (safe: prior reads of buf0 ended before caller's sync)
#pragma unroll
    for (int it = 0; it < 4; ++it) {
        int nb = wave * 2 + (it & 1), ks = it >> 1;
        gl_lds16(Bsrc + (size_t)(nb * 32 + l31) * 512 + ks * 16 + l5,
                 Bp + nb * 1024 + ks * 512);
    }

    for (int p = 0; p < 16; ++p) {
        const int k0 = p * 32;
        __syncthreads();   // panel p landed (vmcnt drain); buf[(p+1)&1] free
        if (p < 15) {
            f16* nbuf = Bp + ((p + 1) & 1) * BP_HALF;
#pragma unroll
            for (int it = 0; it < 4; ++it) {
                int nb = wave * 2 + (it & 1), ks = it >> 1;
                gl_lds16(Bsrc + (size_t)(nb * 32 + l31) * 512 + k0 + 32 + ks * 16 + l5,
                         nbuf + nb * 1024 + ks * 512);
            }
        }
        const f16* cbuf = Bp + (p & 1) * BP_HALF;
#pragma unroll
        for (int dk = 0; dk < 32; dk += 16) {
            f16x8 af[2], bf[2];
#pragma unroll
            for (int mt = 0; mt < 2; ++mt)
                af[mt] = *(const f16x8*)(Sb + (size_t)(mt * 32 + l31) * SB_STRIDE + k0 + dk + l5);
#pragma unroll
            for (int nt = 0; nt < 2; ++nt)
                bf[nt] = *(const f16x8*)(cbuf + (wave * 2 + nt) * 1024 + (dk >> 4) * 512 + lane * 8);
#pragma unroll
            for (int mt = 0; mt < 2; ++mt)
#pragma unroll
                for (int nt = 0; nt < 2; ++nt)
                    acc[mt][nt] = __builtin_amdgcn_mfma_f32_32x32x16_f16(af[mt], bf[nt], acc[mt][nt], 0, 0, 0);
        }
    }
    __syncthreads();  // all waves done reading Sb/Bp -> caller may overwrite Sb
}

// C/D mapping 32x32: col=lane&31, row=(reg&3)+8*(reg>>2)+4*(lane>>5)
__device__ __forceinline__ void emit_to_S(f16* __restrict__ Sb, const f32x16 acc[2][2],
                                          int t, float scale)
{
    const int lane = t & 63;
    const int wn = (t >> 6) * 64;
#pragma unroll
    for (int mt = 0; mt < 2; ++mt)
#pragma unroll
        for (int nt = 0; nt < 2; ++nt) {
            int col = wn + nt * 32 + (lane & 31);
#pragma unroll
            for (int r = 0; r < 16; ++r) {
                int row = mt * 32 + (r & 3) + 8 * (r >> 2) + 4 * (lane >> 5);
                Sb[(size_t)row * SB_STRIDE + col] = (f16)(acc[mt][nt][r] * scale);
            }
        }
}

__global__ __launch_bounds__(512) void chain_f16(
    const f16* __restrict__ q16, const f16* __restrict__ k16,
    const f16* __restrict__ ck16, const f16* __restrict__ vt16,
    const f16* __restrict__ cvt16, float* __restrict__ out)
{
    extern __shared__ f16 smem[];
    f16* Sb = smem;                       // [64][SB_STRIDE]
    f16* Bp = smem + 64 * SB_STRIDE;      // 2 x BP_HALF
    const int t = threadIdx.x;
    const int bh = blockIdx.x >> 3;
    const int q0 = (blockIdx.x & 7) * 64;
    const size_t SB = 512 * 512;

    // stage Q[q0..q0+64) into Sbuf
    const f16* Q = q16 + bh * SB;
    for (int i = t; i < 4096; i += 512) {
        int row = i >> 6, c = (i & 63) * 8;
        *(int4*)(Sb + (size_t)row * SB_STRIDE + c) =
            *(const int4*)(Q + (size_t)(q0 + row) * 512 + c);
    }
    // stage_nt's loop-top sync covers Q-write -> Sb-read

    f32x16 acc[2][2];

    // S1 = Q @ K^T
    stage_nt(k16 + bh * SB, Sb, Bp, t, acc);
    emit_to_S(Sb, acc, t, 1.0f);

    // S2 = S1 @ CK^T * SCALE
    stage_nt(ck16 + bh * SB, Sb, Bp, t, acc);
    emit_to_S(Sb, acc, t, SCALE);
    __syncthreads();

    // softmax rows (wave w -> rows 8w..8w+8)
    {
        const int lane = t & 63;
        const int wave = t >> 6;
        for (int rr = 0; rr < 8; ++rr) {
            int r = wave * 8 + rr;
            f16x8 xv = *(const f16x8*)(Sb + (size_t)r * SB_STRIDE + lane * 8);
            float x[8];
            float mx = -1e30f;
#pragma unroll
            for (int j = 0; j < 8; ++j) { x[j] = (float)xv[j]; mx = fmaxf(mx, x[j]); }
#pragma unroll
            for (int o = 32; o > 0; o >>= 1) mx = fmaxf(mx, __shfl_xor(mx, o));
            float s = 0.f;
#pragma unroll
            for (int j = 0; j < 8; ++j) { x[j] = __expf(x[j] - mx); s += x[j]; }
#pragma unroll
            for (int o = 32; o > 0; o >>= 1) s += __shfl_xor(s, o);
            float inv = 1.0f / s;
            f16x8 ov;
#pragma unroll
            for (int j = 0; j < 8; ++j) ov[j] = (f16)(x[j] * inv);
            *(f16x8*)(Sb + (size_t)r * SB_STRIDE + lane * 8) = ov;
        }
    }
    // stage_nt's loop-top sync covers softmax-write -> Sb-read

    // C1 = P @ V   (Vt is [bh][d][s]: NT-ready)
    stage_nt(vt16 + bh * SB, Sb, Bp, t, acc);
    emit_to_S(Sb, acc, t, 1.0f);

    // OUT = C1 @ CV (CVt NT-ready), merge-heads store f32
    stage_nt(cvt16 + bh * SB, Sb, Bp, t, acc);
    {
        const int lane = t & 63;
        const int wn = (t >> 6) * 64;
        int b = bh >> 2, h = bh & 3;
#pragma unroll
        for (int mt = 0; mt < 2; ++mt)
#pragma unroll
            for (int nt = 0; nt < 2; ++nt) {
                int col = h * 512 + wn + nt * 32 + (lane & 31);
#pragma unroll
                for (int r = 0; r < 16; ++r) {
                    int row = q0 + mt * 32 + (r & 3) + 8 * (r >> 2) + 4 * (lane >> 5);
                    out[((size_t)b * 512 + row) * 2048 + col] = acc[mt][nt][r];
                }
            }
    }
}

// ---------------------------------------------------------------- host
extern "C" void kernel_launch(void* const* d_in, const int* in_sizes, int n_in,
                              void* d_out, int out_size, void* d_ws, size_t ws_size,
                              hipStream_t stream)
{
    const float* hs = (const float*)d_in[0];
    const float* Wf[5] = {(const float*)d_in[1], (const float*)d_in[3],
                          (const float*)d_in[5], (const float*)d_in[7],
                          (const float*)d_in[9]};
    const float* bf[5] = {(const float*)d_in[2], (const float*)d_in[4],
                          (const float*)d_in[6], (const float*)d_in[8],
                          (const float*)d_in[10]};
    float* out = (float*)d_out;

    hipFuncSetAttribute((const void*)chain_f16,
                        hipFuncAttributeMaxDynamicSharedMemorySize, CHAIN_LDS);
    hipFuncSetAttribute((const void*)proj_f16,
                        hipFuncAttributeMaxDynamicSharedMemorySize, PROJ_LDS);

    f16* ws = (f16*)d_ws;
    const size_t WELEM = 2048ULL * 2048;      // 4,194,304
    const size_t FULLACT = 64ULL * 512 * 512; // 16,777,216

    f16* W16[5];
    for (int i = 0; i < 5; ++i) W16[i] = ws + i * WELEM;
    f16* after_w = ws + 5 * WELEM;

    for (int i = 0; i < 5; ++i)
        conv_f32_f16<<<dim3(WELEM / 2048), 256, 0, stream>>>(Wf[i], W16[i], (int)WELEM);

    size_t full_need = (5 * WELEM + FULLACT + 5 * FULLACT) * sizeof(f16);  // 243,269,632
    if (ws_size >= full_need) {
        // ---------------- full path ----------------
        f16* hs16 = after_w;
        f16* act[5];
        for (int i = 0; i < 5; ++i) act[i] = after_w + FULLACT + i * FULLACT;

        conv_f32_f16<<<dim3(FULLACT / 2048), 256, 0, stream>>>(hs, hs16, (int)FULLACT);

        ProjPtrs P;
        for (int i = 0; i < 5; ++i) { P.W[i] = W16[i]; P.bias[i] = bf[i]; P.dst[i] = act[i]; }
        proj_f16<<<dim3(8, 32, 5), 512, PROJ_LDS, stream>>>(hs16, P);

        // act order: q,k,v^T,ck,cv^T -> chain(q,k,ck,vt,cvt)
        chain_f16<<<dim3(512), 512, CHAIN_LDS, stream>>>(
            act[0], act[1], act[3], act[2], act[4], out);
    } else {
        // ---------------- chunked path (54.5 MB ws) ----------------
        const size_t CHROW = 1048576ULL;      // 512*2048 elems per batch
        const size_t CHACT = 4ULL * 512 * 512;
        f16* hs16c = after_w;
        f16* act[5];
        for (int i = 0; i < 5; ++i) act[i] = after_w + CHROW + i * CHACT;

        ProjPtrs P;
        for (int i = 0; i < 5; ++i) { P.W[i] = W16[i]; P.bias[i] = bf[i]; P.dst[i] = act[i]; }

        for (int c = 0; c < 16; ++c) {
            conv_f32_f16<<<dim3(CHROW / 2048), 256, 0, stream>>>(
                hs + c * CHROW, hs16c, (int)CHROW);
            proj_f16<<<dim3(8, 2, 5), 512, PROJ_LDS, stream>>>(hs16c, P);
            chain_f16<<<dim3(32), 512, CHAIN_LDS, stream>>>(
                act[0], act[1], act[3], act[2], act[4], out + c * CHROW);
        }
    }

    (void)in_sizes; (void)n_in; (void)out_size;
}

// Round 4
// 765.035 us; speedup vs baseline: 1.3164x; 1.0237x over previous
//
#include <hip/hip_runtime.h>
#include <math.h>

// TrittentionCube: B=16, S=512, HID=2048, H=4, D=512 (S==D)
// Round 9 (= round 8 resubmit; container failed on infra): proj on the
// 8-phase schedule (T3+T4+T5): 256x256 tile, BK=64, 2 double-buffered 64KB
// K-tiles (128KB LDS), 4 phases per K-tile:
// {quadrant ds_reads || half-tile global_load_lds prefetch} -> barrier ->
// lgkmcnt(0) -> setprio+16 MFMA -> barrier. Staging leads by 1.5 K-tiles;
// vmcnt(4) once per tile (never 0 until tail). Fragment-order LDS keeps
// everything conflict-free with no swizzle. Chain kernel unchanged.

typedef _Float16 f16;
typedef f16 f16x8 __attribute__((ext_vector_type(8)));
typedef float f32x4 __attribute__((ext_vector_type(4)));
typedef float f32x16 __attribute__((ext_vector_type(16)));

#define SB_STRIDE 520            // chain S-buffer row stride (halfs)
#define BP_HALF   16384          // chain 32 KB panel buffer (halfs)
#define CHAIN_LDS ((64 * SB_STRIDE + 2 * BP_HALF) * 2)   // 132,096 B
#define PROJ_LDS  131072         // 2 x 64KB K-tile buffers

static constexpr float SCALE = 0.04419417382415922f;  // 1/sqrt(512)

// async global->LDS, 16B per lane; LDS dest = wave-uniform base + lane*16
__device__ __forceinline__ void gl_lds16(const f16* g, f16* l)
{
    __builtin_amdgcn_global_load_lds(
        (const __attribute__((address_space(1))) void*)g,
        (__attribute__((address_space(3))) void*)l, 16, 0, 0);
}

// ---------------------------------------------------------------- convert
__global__ __launch_bounds__(256) void conv_f32_f16(const float* __restrict__ src,
                                                    f16* __restrict__ dst, int n)
{
    int i = (blockIdx.x * 256 + threadIdx.x) * 8;
    if (i + 8 <= n) {
        float4 a = *(const float4*)(src + i);
        float4 b = *(const float4*)(src + i + 4);
        f16 o[8] = {(f16)a.x, (f16)a.y, (f16)a.z, (f16)a.w,
                    (f16)b.x, (f16)b.y, (f16)b.z, (f16)b.w};
        *(int4*)(dst + i) = *(int4*)o;
    }
}

// ---------------------------------------------------------------- projections
struct ProjPtrs {
    const f16* W[5];
    const float* bias[5];
    f16* dst[5];
};

// C[m,n] = sum_k A[m,k] * W[n,k] + bias[n].  Block 256x256, BK=64,
// 512 threads = 8 waves as 2(M) x 4(N); per-wave output 128x64,
// acc[8][4] of 16x16x32_f16 fragments.
//
// LDS: 2 buffers x 64KB (A-tile 32KB + B-tile 32KB).  Each 32KB tile is two
// 16KB half-tiles (128 rows x 64 k), fragment-order per half:
//   slot s in [0,1024): rg=s>>7, kg=(s>>4)&7, r16=s&15, 8 halfs at s*8.
// Staging: 2 gl_lds per thread per half-tile; LDS dest wave-uniform
// (j*4096 + wave*512 halfs) + HW lane*16B; global addr per-lane.  Write
// mapping j*4096+(w>>1)*1024+(w&1)*512+kq*128+r16*8 == read mapping
// mf*1024+dk*512+kq*128+r16*8 (verified).  Frag reads 1KB-contiguous per
// wave.  Both directions conflict-free, no swizzle.
//
// Schedule per K-tile t (4 phases; quadrant = mf-half x nf-half):
//   P1: ds af[0-3], bf[0-1]; stage B0(t+1) | bar | MFMA m0n0 | bar
//   P2: ds af[4-7];          stage B1(t+1) | bar | MFMA m1n0 | bar
//   P3: ds bf[2-3];          stage A0(t+2) | bar | MFMA m0n1 | bar
//   P4: (no ds);    stage A1(t+2); vmcnt(4) | bar | MFMA m1n1 | bar
// Each phase's ds_reads and its staging target are disjoint LDS regions;
// every region's last read retires >=1 barrier before its overwrite issues.
// vmcnt(4) leaves A(t+2) in flight and guarantees tile t+1 landed.
// z==2 (v) and z==4 (cv) are stored transposed [bh][d][s] for the chain.
__global__ __launch_bounds__(512, 2) void proj_f16(const f16* __restrict__ A, ProjPtrs P)
{
    extern __shared__ f16 sm[];          // 2 * 32768 halfs = 128 KB
    const int z = blockIdx.z;
    const f16* __restrict__ W = P.W[z];
    const float* __restrict__ bias = P.bias[z];
    f16* __restrict__ dst = P.dst[z];
    const bool tr = (z == 2) || (z == 4);

    const int t    = threadIdx.x;
    const int lane = t & 63;
    const int wave = t >> 6;
    const int wr   = wave >> 2, wc = wave & 3;
    const int bm = blockIdx.y * 256, bn = blockIdx.x * 256;
    const int r16 = lane & 15;
    const int kq  = lane >> 4;           // 0..3

    // per-thread global staging bases (slot row = (wave>>1)*16 + r16 within a
    // 128-row half; slot kg = (wave&1)*4 + kq)
    const f16* gA = A + (size_t)(bm + (wave >> 1) * 16 + r16) * 2048 + ((wave & 1) * 4 + kq) * 8;
    const f16* gB = W + (size_t)(bn + (wave >> 1) * 16 + r16) * 2048 + ((wave & 1) * 4 + kq) * 8;
    const int stoff = wave * 512;        // wave-uniform LDS stage offset (halfs)

// stage half-tile h (0/1) of matrix A/B, K-tile tt, into buffer c
#define STG_A(c, h, tt)                                                     \
    {                                                                       \
        f16* d_ = sm + (c) * 32768 + (h) * 8192 + stoff;                    \
        gl_lds16(gA + (size_t)((h) * 128) * 2048 + (tt) * 64, d_);          \
        gl_lds16(gA + (size_t)((h) * 128 + 64) * 2048 + (tt) * 64, d_ + 4096); \
    }
#define STG_B(c, h, tt)                                                     \
    {                                                                       \
        f16* d_ = sm + (c) * 32768 + 16384 + (h) * 8192 + stoff;            \
        gl_lds16(gB + (size_t)((h) * 128) * 2048 + (tt) * 64, d_);          \
        gl_lds16(gB + (size_t)((h) * 128 + 64) * 2048 + (tt) * 64, d_ + 4096); \
    }

    f32x4 acc[8][4];
#pragma unroll
    for (int mf = 0; mf < 8; ++mf)
#pragma unroll
        for (int nf = 0; nf < 4; ++nf)
#pragma unroll
            for (int r = 0; r < 4; ++r) acc[mf][nf][r] = 0.f;

    // prologue: tile 0 (all 4 halves) + tile 1's A-halves; 12 loads.
    STG_A(0, 0, 0); STG_A(0, 1, 0); STG_B(0, 0, 0); STG_B(0, 1, 0);
    STG_A(1, 0, 1); STG_A(1, 1, 1);
    asm volatile("s_waitcnt vmcnt(4)" ::: "memory");   // tile 0 landed
    __builtin_amdgcn_s_barrier();
    asm volatile("" ::: "memory");

    const int aoff = kq * 128 + r16 * 8;   // frag-read lane offset (halfs)

    f16x8 af[8][2], bf[4][2];

    for (int kt = 0; kt < 32; ++kt) {
        const int cur = kt & 1, nxt = cur ^ 1;
        const f16* pa = sm + cur * 32768 + wr * 8192 + aoff;
        const f16* pb = sm + cur * 32768 + 16384 + (wc >> 1) * 8192 + (wc & 1) * 4096 + aoff;

        // ---------------- P1: af[0-3], bf[0-1]; stage B0(kt+1); MFMA m0n0
#pragma unroll
        for (int mf = 0; mf < 4; ++mf)
#pragma unroll
            for (int dk = 0; dk < 2; ++dk)
                af[mf][dk] = *(const f16x8*)(pa + mf * 1024 + dk * 512);
#pragma unroll
        for (int nf = 0; nf < 2; ++nf)
#pragma unroll
            for (int dk = 0; dk < 2; ++dk)
                bf[nf][dk] = *(const f16x8*)(pb + nf * 1024 + dk * 512);
        if (kt + 1 < 32) STG_B(nxt, 0, kt + 1);
        asm volatile("" ::: "memory");
        __builtin_amdgcn_s_barrier();
        asm volatile("s_waitcnt lgkmcnt(0)" ::: "memory");
        __builtin_amdgcn_sched_barrier(0);
        __builtin_amdgcn_s_setprio(1);
#pragma unroll
        for (int mf = 0; mf < 4; ++mf)
#pragma unroll
            for (int nf = 0; nf < 2; ++nf)
#pragma unroll
                for (int dk = 0; dk < 2; ++dk)
                    acc[mf][nf] = __builtin_amdgcn_mfma_f32_16x16x32_f16(
                        af[mf][dk], bf[nf][dk], acc[mf][nf], 0, 0, 0);
        __builtin_amdgcn_s_setprio(0);
        asm volatile("" ::: "memory");
        __builtin_amdgcn_s_barrier();
        asm volatile("" ::: "memory");

        // ---------------- P2: af[4-7]; stage B1(kt+1); MFMA m1n0
#pragma unroll
        for (int mf = 4; mf < 8; ++mf)
#pragma unroll
            for (int dk = 0; dk < 2; ++dk)
                af[mf][dk] = *(const f16x8*)(pa + mf * 1024 + dk * 512);
        if (kt + 1 < 32) STG_B(nxt, 1, kt + 1);
        asm volatile("" ::: "memory");
        __builtin_amdgcn_s_barrier();
        asm volatile("s_waitcnt lgkmcnt(0)" ::: "memory");
        __builtin_amdgcn_sched_barrier(0);
        __builtin_amdgcn_s_setprio(1);
#pragma unroll
        for (int mf = 4; mf < 8; ++mf)
#pragma unroll
            for (int nf = 0; nf < 2; ++nf)
#pragma unroll
                for (int dk = 0; dk < 2; ++dk)
                    acc[mf][nf] = __builtin_amdgcn_mfma_f32_16x16x32_f16(
                        af[mf][dk], bf[nf][dk], acc[mf][nf], 0, 0, 0);
        __builtin_amdgcn_s_setprio(0);
        asm volatile("" ::: "memory");
        __builtin_amdgcn_s_barrier();
        asm volatile("" ::: "memory");

        // ---------------- P3: bf[2-3]; stage A0(kt+2); MFMA m0n1
#pragma unroll
        for (int nf = 2; nf < 4; ++nf)
#pragma unroll
            for (int dk = 0; dk < 2; ++dk)
                bf[nf][dk] = *(const f16x8*)(pb + nf * 1024 + dk * 512);
        if (kt + 2 < 32) STG_A(cur, 0, kt + 2);
        asm volatile("" ::: "memory");
        __builtin_amdgcn_s_barrier();
        asm volatile("s_waitcnt lgkmcnt(0)" ::: "memory");
        __builtin_amdgcn_sched_barrier(0);
        __builtin_amdgcn_s_setprio(1);
#pragma unroll
        for (int mf = 0; mf < 4; ++mf)
#pragma unroll
            for (int nf = 2; nf < 4; ++nf)
#pragma unroll
                for (int dk = 0; dk < 2; ++dk)
                    acc[mf][nf] = __builtin_amdgcn_mfma_f32_16x16x32_f16(
                        af[mf][dk], bf[nf][dk], acc[mf][nf], 0, 0, 0);
        __builtin_amdgcn_s_setprio(0);
        asm volatile("" ::: "memory");
        __builtin_amdgcn_s_barrier();
        asm volatile("" ::: "memory");

        // ---------------- P4: stage A1(kt+2); vmcnt; MFMA m1n1
        if (kt + 2 < 32) STG_A(cur, 1, kt + 2);
        if (kt < 30) asm volatile("s_waitcnt vmcnt(4)" ::: "memory");
        else         asm volatile("s_waitcnt vmcnt(0)" ::: "memory");
        __builtin_amdgcn_s_barrier();
        asm volatile("" ::: "memory");
        __builtin_amdgcn_s_setprio(1);
#pragma unroll
        for (int mf = 4; mf < 8; ++mf)
#pragma unroll
            for (int nf = 2; nf < 4; ++nf)
#pragma unroll
                for (int dk = 0; dk < 2; ++dk)
                    acc[mf][nf] = __builtin_amdgcn_mfma_f32_16x16x32_f16(
                        af[mf][dk], bf[nf][dk], acc[mf][nf], 0, 0, 0);
        __builtin_amdgcn_s_setprio(0);
        asm volatile("" ::: "memory");
        __builtin_amdgcn_s_barrier();
        asm volatile("" ::: "memory");
    }
#undef STG_A
#undef STG_B

    // epilogue: C/D mapping col(n)=lane&15, row(m)=(lane>>4)*4+reg
    const int wm = wr * 128, wn = wc * 64;
#pragma unroll
    for (int nf = 0; nf < 4; ++nf) {
        int n = bn + wn + nf * 16 + r16;
        float bb = bias[n];
        int h = n >> 9, d = n & 511;
#pragma unroll
        for (int mf = 0; mf < 8; ++mf) {
            int mbase = bm + wm + mf * 16 + (lane >> 4) * 4;
            int b = mbase >> 9, s0 = mbase & 511;
            if (!tr) {
#pragma unroll
                for (int r = 0; r < 4; ++r)
                    dst[(((size_t)(b * 4 + h)) * 512 + s0 + r) * 512 + d] =
                        (f16)(acc[mf][nf][r] + bb);
            } else {
                f16 pk[4];
#pragma unroll
                for (int r = 0; r < 4; ++r) pk[r] = (f16)(acc[mf][nf][r] + bb);
                *(float2*)(dst + (((size_t)(b * 4 + h)) * 512 + d) * 512 + s0) =
                    *(float2*)pk;
            }
        }
    }
}

// ---------------------------------------------------------------- fused chain
// 512 threads, 8 waves; wave w owns 64-col n-strip, acc[2][2] (64x512 tile).
// acc = Sb(64xK=512) @ Bsrc^T, Bsrc row-major [n][k] (ld=512).
// B-panel (k=32) layout: [nb 16][ks 2][n 32][8 halfs], double-buffered,
// staged with global_load_lds; panel p+1 in flight during panel p compute.
__device__ __forceinline__ void stage_nt(
    const f16* __restrict__ Bsrc,
    f16* __restrict__ Sb, f16* __restrict__ Bp, int t, f32x16 acc[2][2])
{
    const int lane = t & 63;
    const int wave = t >> 6;
    const int l31  = lane & 31;
    const int l5   = (lane >> 5) * 8;

#pragma unroll
    for (int mt = 0; mt < 2; ++mt)
#pragma unroll
        for (int nt = 0; nt < 2; ++nt)
#pragma unroll
            for (int r = 0; r < 16; ++r) acc[mt][nt][r] = 0.f;

    // issue panel 0 -> buf0 (safe: prior reads of buf0 ended before caller's sync)
#pragma unroll
    for (int it = 0; it < 4; ++it) {
        int nb = wave * 2 + (it & 1), ks = it >> 1;
        gl_lds16(Bsrc + (size_t)(nb * 32 + l31) * 512 + ks * 16 + l5,
                 Bp + nb * 1024 + ks * 512);
    }

    for (int p = 0; p < 16; ++p) {
        const int k0 = p * 32;
        __syncthreads();   // panel p landed (vmcnt drain); buf[(p+1)&1] free
        if (p < 15) {
            f16* nbuf = Bp + ((p + 1) & 1) * BP_HALF;
#pragma unroll
            for (int it = 0; it < 4; ++it) {
                int nb = wave * 2 + (it & 1), ks = it >> 1;
                gl_lds16(Bsrc + (size_t)(nb * 32 + l31) * 512 + k0 + 32 + ks * 16 + l5,
                         nbuf + nb * 1024 + ks * 512);
            }
        }
        const f16* cbuf = Bp + (p & 1) * BP_HALF;
#pragma unroll
        for (int dk = 0; dk < 32; dk += 16) {
            f16x8 af[2], bf[2];
#pragma unroll
            for (int mt = 0; mt < 2; ++mt)
                af[mt] = *(const f16x8*)(Sb + (size_t)(mt * 32 + l31) * SB_STRIDE + k0 + dk + l5);
#pragma unroll
            for (int nt = 0; nt < 2; ++nt)
                bf[nt] = *(const f16x8*)(cbuf + (wave * 2 + nt) * 1024 + (dk >> 4) * 512 + lane * 8);
#pragma unroll
            for (int mt = 0; mt < 2; ++mt)
#pragma unroll
                for (int nt = 0; nt < 2; ++nt)
                    acc[mt][nt] = __builtin_amdgcn_mfma_f32_32x32x16_f16(af[mt], bf[nt], acc[mt][nt], 0, 0, 0);
        }
    }
    __syncthreads();  // all waves done reading Sb/Bp -> caller may overwrite Sb
}

// C/D mapping 32x32: col=lane&31, row=(reg&3)+8*(reg>>2)+4*(lane>>5)
__device__ __forceinline__ void emit_to_S(f16* __restrict__ Sb, const f32x16 acc[2][2],
                                          int t, float scale)
{
    const int lane = t & 63;
    const int wn = (t >> 6) * 64;
#pragma unroll
    for (int mt = 0; mt < 2; ++mt)
#pragma unroll
        for (int nt = 0; nt < 2; ++nt) {
            int col = wn + nt * 32 + (lane & 31);
#pragma unroll
            for (int r = 0; r < 16; ++r) {
                int row = mt * 32 + (r & 3) + 8 * (r >> 2) + 4 * (lane >> 5);
                Sb[(size_t)row * SB_STRIDE + col] = (f16)(acc[mt][nt][r] * scale);
            }
        }
}

__global__ __launch_bounds__(512) void chain_f16(
    const f16* __restrict__ q16, const f16* __restrict__ k16,
    const f16* __restrict__ ck16, const f16* __restrict__ vt16,
    const f16* __restrict__ cvt16, float* __restrict__ out)
{
    extern __shared__ f16 smem[];
    f16* Sb = smem;                       // [64][SB_STRIDE]
    f16* Bp = smem + 64 * SB_STRIDE;      // 2 x BP_HALF
    const int t = threadIdx.x;
    const int bh = blockIdx.x >> 3;
    const int q0 = (blockIdx.x & 7) * 64;
    const size_t SB = 512 * 512;

    // stage Q[q0..q0+64) into Sbuf
    const f16* Q = q16 + bh * SB;
    for (int i = t; i < 4096; i += 512) {
        int row = i >> 6, c = (i & 63) * 8;
        *(int4*)(Sb + (size_t)row * SB_STRIDE + c) =
            *(const int4*)(Q + (size_t)(q0 + row) * 512 + c);
    }
    // stage_nt's loop-top sync covers Q-write -> Sb-read

    f32x16 acc[2][2];

    // S1 = Q @ K^T
    stage_nt(k16 + bh * SB, Sb, Bp, t, acc);
    emit_to_S(Sb, acc, t, 1.0f);

    // S2 = S1 @ CK^T * SCALE
    stage_nt(ck16 + bh * SB, Sb, Bp, t, acc);
    emit_to_S(Sb, acc, t, SCALE);
    __syncthreads();

    // softmax rows (wave w -> rows 8w..8w+8)
    {
        const int lane = t & 63;
        const int wave = t >> 6;
        for (int rr = 0; rr < 8; ++rr) {
            int r = wave * 8 + rr;
            f16x8 xv = *(const f16x8*)(Sb + (size_t)r * SB_STRIDE + lane * 8);
            float x[8];
            float mx = -1e30f;
#pragma unroll
            for (int j = 0; j < 8; ++j) { x[j] = (float)xv[j]; mx = fmaxf(mx, x[j]); }
#pragma unroll
            for (int o = 32; o > 0; o >>= 1) mx = fmaxf(mx, __shfl_xor(mx, o));
            float s = 0.f;
#pragma unroll
            for (int j = 0; j < 8; ++j) { x[j] = __expf(x[j] - mx); s += x[j]; }
#pragma unroll
            for (int o = 32; o > 0; o >>= 1) s += __shfl_xor(s, o);
            float inv = 1.0f / s;
            f16x8 ov;
#pragma unroll
            for (int j = 0; j < 8; ++j) ov[j] = (f16)(x[j] * inv);
            *(f16x8*)(Sb + (size_t)r * SB_STRIDE + lane * 8) = ov;
        }
    }
    // stage_nt's loop-top sync covers softmax-write -> Sb-read

    // C1 = P @ V   (Vt is [bh][d][s]: NT-ready)
    stage_nt(vt16 + bh * SB, Sb, Bp, t, acc);
    emit_to_S(Sb, acc, t, 1.0f);

    // OUT = C1 @ CV (CVt NT-ready), merge-heads store f32
    stage_nt(cvt16 + bh * SB, Sb, Bp, t, acc);
    {
        const int lane = t & 63;
        const int wn = (t >> 6) * 64;
        int b = bh >> 2, h = bh & 3;
#pragma unroll
        for (int mt = 0; mt < 2; ++mt)
#pragma unroll
            for (int nt = 0; nt < 2; ++nt) {
                int col = h * 512 + wn + nt * 32 + (lane & 31);
#pragma unroll
                for (int r = 0; r < 16; ++r) {
                    int row = q0 + mt * 32 + (r & 3) + 8 * (r >> 2) + 4 * (lane >> 5);
                    out[((size_t)b * 512 + row) * 2048 + col] = acc[mt][nt][r];
                }
            }
    }
}

// ---------------------------------------------------------------- host
extern "C" void kernel_launch(void* const* d_in, const int* in_sizes, int n_in,
                              void* d_out, int out_size, void* d_ws, size_t ws_size,
                              hipStream_t stream)
{
    const float* hs = (const float*)d_in[0];
    const float* Wf[5] = {(const float*)d_in[1], (const float*)d_in[3],
                          (const float*)d_in[5], (const float*)d_in[7],
                          (const float*)d_in[9]};
    const float* bf[5] = {(const float*)d_in[2], (const float*)d_in[4],
                          (const float*)d_in[6], (const float*)d_in[8],
                          (const float*)d_in[10]};
    float* out = (float*)d_out;

    hipFuncSetAttribute((const void*)chain_f16,
                        hipFuncAttributeMaxDynamicSharedMemorySize, CHAIN_LDS);
    hipFuncSetAttribute((const void*)proj_f16,
                        hipFuncAttributeMaxDynamicSharedMemorySize, PROJ_LDS);

    f16* ws = (f16*)d_ws;
    const size_t WELEM = 2048ULL * 2048;      // 4,194,304
    const size_t FULLACT = 64ULL * 512 * 512; // 16,777,216

    f16* W16[5];
    for (int i = 0; i < 5; ++i) W16[i] = ws + i * WELEM;
    f16* after_w = ws + 5 * WELEM;

    for (int i = 0; i < 5; ++i)
        conv_f32_f16<<<dim3(WELEM / 2048), 256, 0, stream>>>(Wf[i], W16[i], (int)WELEM);

    size_t full_need = (5 * WELEM + FULLACT + 5 * FULLACT) * sizeof(f16);  // 243,269,632
    if (ws_size >= full_need) {
        // ---------------- full path ----------------
        f16* hs16 = after_w;
        f16* act[5];
        for (int i = 0; i < 5; ++i) act[i] = after_w + FULLACT + i * FULLACT;

        conv_f32_f16<<<dim3(FULLACT / 2048), 256, 0, stream>>>(hs, hs16, (int)FULLACT);

        ProjPtrs P;
        for (int i = 0; i < 5; ++i) { P.W[i] = W16[i]; P.bias[i] = bf[i]; P.dst[i] = act[i]; }
        proj_f16<<<dim3(8, 32, 5), 512, PROJ_LDS, stream>>>(hs16, P);

        // act order: q,k,v^T,ck,cv^T -> chain(q,k,ck,vt,cvt)
        chain_f16<<<dim3(512), 512, CHAIN_LDS, stream>>>(
            act[0], act[1], act[3], act[2], act[4], out);
    } else {
        // ---------------- chunked path (54.5 MB ws) ----------------
        const size_t CHROW = 1048576ULL;      // 512*2048 elems per batch
        const size_t CHACT = 4ULL * 512 * 512;
        f16* hs16c = after_w;
        f16* act[5];
        for (int i = 0; i < 5; ++i) act[i] = after_w + CHROW + i * CHACT;

        ProjPtrs P;
        for (int i = 0; i < 5; ++i) { P.W[i] = W16[i]; P.bias[i] = bf[i]; P.dst[i] = act[i]; }

        for (int c = 0; c < 16; ++c) {
            conv_f32_f16<<<dim3(CHROW / 2048), 256, 0, stream>>>(
                hs + c * CHROW, hs16c, (int)CHROW);
            proj_f16<<<dim3(8, 2, 5), 512, PROJ_LDS, stream>>>(hs16c, P);
            chain_f16<<<dim3(32), 512, CHAIN_LDS, stream>>>(
                act[0], act[1], act[3], act[2], act[4], out + c * CHROW);
        }
    }

    (void)in_sizes; (void)n_in; (void)out_size;
}